// Round 6
// baseline (281.491 us; speedup 1.0000x reference)
//
#include <hip/hip_runtime.h>

#define T_MAX 512
#define BATCH 32
#define CLASSES 1296
#define L_MAX 64
#define NROWS (T_MAX * BATCH)   // 16384
#define NINF (-INFINITY)
#define NSEQBLK 2048            // 8 seq rows per 512-thread block
#define NPREDBLK 2048           // 8 pred rows per 512-thread block

// DPP wave64 sum: row_shr 1/2/4/8 + row_bcast 15/31. Total lands in LANE 63.
__device__ __forceinline__ float wave_sum64(float v) {
    v += __int_as_float(__builtin_amdgcn_update_dpp(0, __float_as_int(v), 0x111, 0xF, 0xF, true));
    v += __int_as_float(__builtin_amdgcn_update_dpp(0, __float_as_int(v), 0x112, 0xF, 0xF, true));
    v += __int_as_float(__builtin_amdgcn_update_dpp(0, __float_as_int(v), 0x114, 0xF, 0xF, true));
    v += __int_as_float(__builtin_amdgcn_update_dpp(0, __float_as_int(v), 0x118, 0xF, 0xF, true));
    v += __int_as_float(__builtin_amdgcn_update_dpp(0, __float_as_int(v), 0x142, 0xF, 0xF, true));
    v += __int_as_float(__builtin_amdgcn_update_dpp(0, __float_as_int(v), 0x143, 0xF, 0xF, true));
    return v;
}

// ---------------------------------------------------------------------------
// K1: seq rowstats + compact pb staging (verified structure). One wave per
// seq row: exp-sum, DPP reduce, row->LDS, label gather, coalesced 256-B pb
// row of RAW logits (the DP is invariant to the log-softmax shift). Kernel
// boundary publishes pb/lse_seq. Also zeroes the K2 counters.
// ---------------------------------------------------------------------------
__global__ __launch_bounds__(512, 4) void seq_kernel(
    const float* __restrict__ seqp, const int* __restrict__ label,
    float* __restrict__ lse_seq, float* __restrict__ pb,
    int* __restrict__ predDone, int* __restrict__ partCnt)
{
    __shared__ float rowbuf[8][CLASSES];   // 41.5 KB
    const int w = threadIdx.x >> 6, lane = threadIdx.x & 63;
    if (blockIdx.x == 0 && threadIdx.x == 0) { *predDone = 0; *partCnt = 0; }

    const int r = (blockIdx.x << 3) + w;           // [0, NROWS)
    const int b = r & 31, t = r >> 5;
    const float* xs = seqp + (size_t)r * CLASSES;
    const float4* s4 = (const float4*)xs;

    float4 b0 = s4[lane],       b1 = s4[lane + 64],  b2 = s4[lane + 128];
    float4 b3 = s4[lane + 192], b4 = s4[lane + 256];
    float4 bt = make_float4(0.f, 0.f, 0.f, 0.f);
    if (lane < 4) bt = s4[320 + lane];
    const int lab = label[(b << 6) + lane];

    // stage the row to LDS for the label gather (single wave, no barrier)
    float4* rb4 = (float4*)rowbuf[w];
    rb4[lane] = b0; rb4[lane + 64] = b1; rb4[lane + 128] = b2;
    rb4[lane + 192] = b3; rb4[lane + 256] = b4;
    if (lane < 4) rb4[320 + lane] = bt;

    float ss = __expf(b0.x) + __expf(b0.y) + __expf(b0.z) + __expf(b0.w)
             + __expf(b1.x) + __expf(b1.y) + __expf(b1.z) + __expf(b1.w)
             + __expf(b2.x) + __expf(b2.y) + __expf(b2.z) + __expf(b2.w)
             + __expf(b3.x) + __expf(b3.y) + __expf(b3.z) + __expf(b3.w)
             + __expf(b4.x) + __expf(b4.y) + __expf(b4.z) + __expf(b4.w);
    if (lane < 4)
        ss += __expf(bt.x) + __expf(bt.y) + __expf(bt.z) + __expf(bt.w);
    ss = wave_sum64(ss);
    if (lane == 63) lse_seq[r] = __logf(ss);

    pb[(((size_t)(b << 9) + t) << 6) + lane] = rowbuf[w][lab];
}

// ---------------------------------------------------------------------------
// K2: FUSED.
//   blocks 0..31   : align DP for batch b. Wave 0 stages the whole pb panel
//                    through a 3-slot x 64-col LDS ring (global_load_lds,
//                    counted vmcnt(32) => 2 sub-panels of compute in flight
//                    cover L3 latency even under congestion), runs the
//                    verified DPP chain from LDS, backtracks, fills rows_s.
//                    Then the block spins until all pred blocks are done and
//                    computes CE for its own batch (no tg, no 3rd kernel).
//   blocks 32..2079: pred rowstats. These hold the CLOCK at max while the
//                    serial chains run (round 5: align alone = downclocked
//                    76 us; the chain itself is ~5 us at full clock).
//                    They publish lse/sum via agent-relaxed stores + one
//                    per-block release increment (cheap: nothing dirty in L2).
// ---------------------------------------------------------------------------
__global__ __launch_bounds__(512, 2) void fused_kernel(
    const float* __restrict__ pred, const float* __restrict__ pb,
    const int* __restrict__ label, const int* __restrict__ x_len,
    const int* __restrict__ label_len,
    float* __restrict__ lse_pred, float* __restrict__ sum_pred,
    const float* __restrict__ lse_seq,
    float* __restrict__ partials, int* __restrict__ predDone,
    int* __restrict__ partCnt, float* __restrict__ out)
{
    __shared__ float ring[3][64 * 64];   // 3 sub-panels x 64 cols x 64 lanes (48 KB)
    __shared__ unsigned chw[16][64];     // choice bits [panel][lane] (4 KB)
    __shared__ int a_s[64];
    __shared__ int rows_s[T_MAX];
    __shared__ float sm[8];
    const int w = threadIdx.x >> 6, lane = threadIdx.x & 63;

    if (blockIdx.x >= 32) {
        // ---------------- pred rowstats: one wave per row ----------------
        const int r = ((blockIdx.x - 32) << 3) + w;   // [0, NROWS)
        const float* xp = pred + (size_t)r * CLASSES;
        const float4* p4 = (const float4*)xp;

        float4 a0 = p4[lane],       a1 = p4[lane + 64],  a2 = p4[lane + 128];
        float4 a3 = p4[lane + 192], a4 = p4[lane + 256];
        float4 at = make_float4(0.f, 0.f, 0.f, 0.f);
        if (lane < 4) at = p4[320 + lane];

        float sp = __expf(a0.x) + __expf(a0.y) + __expf(a0.z) + __expf(a0.w)
                 + __expf(a1.x) + __expf(a1.y) + __expf(a1.z) + __expf(a1.w)
                 + __expf(a2.x) + __expf(a2.y) + __expf(a2.z) + __expf(a2.w)
                 + __expf(a3.x) + __expf(a3.y) + __expf(a3.z) + __expf(a3.w)
                 + __expf(a4.x) + __expf(a4.y) + __expf(a4.z) + __expf(a4.w);
        float sx = (a0.x + a0.y + a0.z + a0.w) + (a1.x + a1.y + a1.z + a1.w)
                 + (a2.x + a2.y + a2.z + a2.w) + (a3.x + a3.y + a3.z + a3.w)
                 + (a4.x + a4.y + a4.z + a4.w);
        if (lane < 4) {
            sp += __expf(at.x) + __expf(at.y) + __expf(at.z) + __expf(at.w);
            sx += at.x + at.y + at.z + at.w;
        }
        sp = wave_sum64(sp);
        sx = wave_sum64(sx);
        if (lane == 63) {
            // agent-scope relaxed: device-visible without an L2 flush
            __hip_atomic_store(&lse_pred[r], __logf(sp), __ATOMIC_RELAXED, __HIP_MEMORY_SCOPE_AGENT);
            __hip_atomic_store(&sum_pred[r], sx, __ATOMIC_RELAXED, __HIP_MEMORY_SCOPE_AGENT);
        }
        __syncthreads();   // drains the stores before the release
        if (threadIdx.x == 0)
            __hip_atomic_fetch_add(predDone, 1, __ATOMIC_RELEASE, __HIP_MEMORY_SCOPE_AGENT);
        return;
    }

    // ---------------- align path: one batch per block ----------------
    const int b = blockIdx.x;
    const int C = x_len[b], R = label_len[b];
    const int limit = C - R;
    const float* pbb = pb + ((size_t)b << 15);     // b * 512 * 64
    const int P = (C + 31) >> 5;                   // 32-col panels, in [8,16]
    const int SS = (P + 1) >> 1;                   // 64-col sub-panels
    const float biasR = (lane < R) ? 0.f : NINF;
    const bool isb0 = (lane & 15) == 0;
    const int ninf_i = 0xFF800000;

    if (w == 0) {
        float dp = NINF;

#define STAGE(S) { const int s_ = (S); if (s_ < SS) {                          \
        const char* src_ = (const char*)pbb + ((size_t)s_ << 14) + lane * 16;  \
        float* dst_ = ring[s_ % 3];                                            \
        _Pragma("unroll")                                                      \
        for (int k = 0; k < 16; ++k)                                           \
            __builtin_amdgcn_global_load_lds(                                  \
                (const __attribute__((address_space(1))) void*)(src_ + (k << 10)), \
                (__attribute__((address_space(3))) void*)(dst_ + (k << 8)), 16, 0, 0); } }

        STAGE(0) STAGE(1) STAGE(2)
        for (int s = 0; s < SS; ++s) {
            // sub-panel s landed iff <= 32 loads (s+1, s+2) still outstanding
            asm volatile("s_waitcnt vmcnt(32)" ::: "memory");
            const float* sp_ = ring[s % 3];
            #pragma unroll
            for (int half = 0; half < 2; ++half) {
                const int pp = (s << 1) + half;
                if (pp >= P) break;
                unsigned w0 = 0;
                #pragma unroll
                for (int g = 0; g < 2; ++g) {
                    const int g_ = (pp << 1) + g;          // global 16-col group
                    float v[16];
                    #pragma unroll
                    for (int u = 0; u < 16; ++u)
                        v[u] = sp_[(((half << 1) + g) << 4) * 64 + (u << 6) + lane];
                    const bool general = (g_ < 2) || (((g_ << 4) + 15) > limit);
                    #pragma unroll
                    for (int u = 0; u < 16; ++u) {
                        const int kk = (g << 4) + u;       // bit within panel word
                        const int j = (g_ << 4) + u;
                        float val;
                        if (general) {
                            if (g_ == 0 && u == 0) {       // column 0 init
                                dp = (lane == 0) ? v[0] : NINF;
                                continue;
                            }
                            const bool ib = (lane <= j) && (lane >= j - limit) && (lane < R);
                            val = ib ? v[u] : NINF;
                        } else {
                            val = v[u] + biasR;            // off-chain R mask
                        }
                        const int dpb = __float_as_int(dp);
                        const int t1 = __builtin_amdgcn_update_dpp(ninf_i, dpb, 0x111, 0xF, 0xF, false); // row_shr:1
                        const int t2 = __builtin_amdgcn_update_dpp(ninf_i, dpb, 0x142, 0xF, 0xF, false); // row_bcast15
                        const float shifted = __int_as_float(isb0 ? t2 : t1);
                        const bool c = shifted > dp;       // strict, off chain
                        w0 |= (c ? 1u : 0u) << kk;
                        dp = fmaxf(shifted, dp) + val;     // == reference select
                    }
                }
                chw[pp][lane] = w0;
            }
            STAGE(s + 3)
        }
        asm volatile("s_waitcnt vmcnt(0)" ::: "memory");
#undef STAGE

        // backtrack: per-row jumps via highest set bit in cached words
        if (lane == 0) {
            int row = R - 1, j = C - 1;
            while (row > 0 && j >= 0) {
                unsigned word = chw[j >> 5][row];
                unsigned mb = (2u << (j & 31)) - 1;
                unsigned m = word & mb;
                if (m) {
                    int hb = 31 - __clz(m);
                    int aj = (j & ~31) | hb;
                    a_s[row] = aj;
                    row--; j = aj - 1;
                } else {
                    j = (j & ~31) - 1;
                }
            }
            for (int i = row; i >= 0; --i) a_s[i] = 0;
        }
        // parallel interval fill: row i occupies [a_s[i], b_i]
        if (lane < R) {
            int a = a_s[lane];
            int bi = (lane == R - 1) ? (C - 1) : (a_s[lane + 1] - 1);
            for (int j = a; j <= bi; ++j) rows_s[j] = lane;
        }
    }
    __syncthreads();                      // rows_s ready for all 8 waves

    // wait until all pred blocks published lse_pred/sum_pred
    if (threadIdx.x == 0) {
        while (__hip_atomic_load(predDone, __ATOMIC_ACQUIRE, __HIP_MEMORY_SCOPE_AGENT) < NPREDBLK)
            __builtin_amdgcn_s_sleep(8);
    }
    __syncthreads();

    // ---- CE for this batch: one t per thread ----
    const int t = threadIdx.x;            // 512 threads == T_MAX
    float ce = 0.f;
    if (t < C) {
        const int e = (t << 5) + b;
        const int row = rows_s[t];
        const int tgt = label[(b << 6) + row];
        const float lp = __hip_atomic_load(&lse_pred[e], __ATOMIC_RELAXED, __HIP_MEMORY_SCOPE_AGENT);
        const float sx = __hip_atomic_load(&sum_pred[e], __ATOMIC_RELAXED, __HIP_MEMORY_SCOPE_AGENT);
        const float S = sx - (float)CLASSES * lp;          // sum_v log_softmax(pred)
        const float lsp_t = pred[(size_t)e * CLASSES + tgt] - lp;
        const float conf = __expf(pbb[((size_t)t << 6) + row] - lse_seq[e]);
        const float smooth = (1.f - conf) * (1.f / (float)(CLASSES - 1));
        ce = -((conf - smooth) * lsp_t + smooth * S);
    }
    ce = wave_sum64(ce);                  // wave total in lane 63
    if (lane == 63) sm[w] = ce;
    __syncthreads();
    if (threadIdx.x == 0) {
        float p = sm[0] + sm[1] + sm[2] + sm[3] + sm[4] + sm[5] + sm[6] + sm[7];
        __hip_atomic_store(&partials[b], p, __ATOMIC_RELEASE, __HIP_MEMORY_SCOPE_AGENT);
        if (__hip_atomic_fetch_add(partCnt, 1, __ATOMIC_ACQ_REL, __HIP_MEMORY_SCOPE_AGENT) == 31) {
            float v = 0.f;
            for (int i = 0; i < 32; ++i)  // fixed order -> deterministic
                v += __hip_atomic_load(&partials[i], __ATOMIC_ACQUIRE, __HIP_MEMORY_SCOPE_AGENT);
            out[0] = v * (1.0f / (float)NROWS);
        }
    }
}

extern "C" void kernel_launch(void* const* d_in, const int* in_sizes, int n_in,
                              void* d_out, int out_size, void* d_ws, size_t ws_size,
                              hipStream_t stream) {
    const float* pred      = (const float*)d_in[0];
    const float* seq_pred  = (const float*)d_in[1];
    const int*   label     = (const int*)d_in[2];
    const int*   x_len     = (const int*)d_in[3];
    const int*   label_len = (const int*)d_in[4];
    float* out = (float*)d_out;

    // workspace layout (floats)
    float* ws = (float*)d_ws;
    float* lse_pred = ws;                      // 16384
    float* sum_pred = ws + NROWS;              // 16384
    float* lse_seq  = ws + 2 * NROWS;          // 16384
    float* pb       = ws + 3 * NROWS;          // 32*512*64 = 1048576
    float* partials = pb + (size_t)BATCH * T_MAX * 64;  // 32
    int*   predDone = (int*)(partials + 32);   // 1
    int*   partCnt  = predDone + 1;            // 1

    seq_kernel<<<NSEQBLK, 512, 0, stream>>>(seq_pred, label, lse_seq, pb,
                                            predDone, partCnt);
    fused_kernel<<<32 + NPREDBLK, 512, 0, stream>>>(
        pred, pb, label, x_len, label_len,
        lse_pred, sum_pred, lse_seq, partials, predDone, partCnt, out);
}

// Round 7
// 205.422 us; speedup vs baseline: 1.3703x; 1.3703x over previous
//
#include <hip/hip_runtime.h>

#define T_MAX 512
#define BATCH 32
#define CLASSES 1296
#define L_MAX 64
#define NROWS (T_MAX * BATCH)   // 16384
#define NINF (-INFINITY)

// DPP wave64 sum: row_shr 1/2/4/8 + row_bcast 15/31. Total lands in LANE 63.
__device__ __forceinline__ float wave_sum64(float v) {
    v += __int_as_float(__builtin_amdgcn_update_dpp(0, __float_as_int(v), 0x111, 0xF, 0xF, true));
    v += __int_as_float(__builtin_amdgcn_update_dpp(0, __float_as_int(v), 0x112, 0xF, 0xF, true));
    v += __int_as_float(__builtin_amdgcn_update_dpp(0, __float_as_int(v), 0x114, 0xF, 0xF, true));
    v += __int_as_float(__builtin_amdgcn_update_dpp(0, __float_as_int(v), 0x118, 0xF, 0xF, true));
    v += __int_as_float(__builtin_amdgcn_update_dpp(0, __float_as_int(v), 0x142, 0xF, 0xF, true));
    v += __int_as_float(__builtin_amdgcn_update_dpp(0, __float_as_int(v), 0x143, 0xF, 0xF, true));
    return v;
}

// ---------------------------------------------------------------------------
// K1: seq rowstats + compact pb staging (verified). One wave per seq row:
// exp-sum, DPP reduce, label gather from the L1-warm row -> coalesced 256-B
// pb row of RAW logits (DP is invariant to the log-softmax shift). Kernel
// boundary publishes pb (rounds 3/6: in-kernel agent-scope sync is poison).
// ---------------------------------------------------------------------------
__global__ __launch_bounds__(256) void seq_rowstats_kernel(
    const float* __restrict__ seqp, const int* __restrict__ label,
    float* __restrict__ lse_seq, float* __restrict__ pb, int* __restrict__ counter)
{
    int r = blockIdx.x * 4 + (threadIdx.x >> 6);   // seq row in [0, NROWS)
    int lane = threadIdx.x & 63;
    if (r == 0 && lane == 0) *counter = 0;
    const float* xs = seqp + (size_t)r * CLASSES;
    const float4* s4 = (const float4*)xs;

    float4 b0 = s4[lane],       b1 = s4[lane + 64],  b2 = s4[lane + 128];
    float4 b3 = s4[lane + 192], b4 = s4[lane + 256];
    float4 bt = make_float4(0.f, 0.f, 0.f, 0.f);
    if (lane < 4) bt = s4[320 + lane];
    int lab = label[((r & 31) << 6) + lane];

    float ss = __expf(b0.x) + __expf(b0.y) + __expf(b0.z) + __expf(b0.w)
             + __expf(b1.x) + __expf(b1.y) + __expf(b1.z) + __expf(b1.w)
             + __expf(b2.x) + __expf(b2.y) + __expf(b2.z) + __expf(b2.w)
             + __expf(b3.x) + __expf(b3.y) + __expf(b3.z) + __expf(b3.w)
             + __expf(b4.x) + __expf(b4.y) + __expf(b4.z) + __expf(b4.w);
    if (lane < 4)
        ss += __expf(bt.x) + __expf(bt.y) + __expf(bt.z) + __expf(bt.w);
    ss = wave_sum64(ss);

    int b = r & 31, t = r >> 5;
    pb[(((size_t)(b << 9) + t) << 6) + lane] = xs[lab];   // row is L1-warm
    if (lane == 63) lse_seq[r] = __logf(ss);
}

// ---------------------------------------------------------------------------
// K2: FUSED, no cross-block sync.
//   blocks 0..31   : align DP for batch b, ONE wave. pb panel staged through
//                    a 3-slot x 64-col LDS ring (global_load_lds, counted
//                    vmcnt: 2 sub-panels = ~2800 compute-cycles in flight,
//                    covers congested L2/L3 latency). Chain runs from LDS,
//                    backtracks, writes tg. Finishes INSIDE the streaming
//                    window at full clock (round 5: align alone downclocks).
//   blocks 32..2079: pred rowstats -- hold the clock and hide the chains.
// ---------------------------------------------------------------------------
__global__ __launch_bounds__(512, 2) void fused_align_pred_kernel(
    const float* __restrict__ pred, const float* __restrict__ pb,
    const int* __restrict__ x_len, const int* __restrict__ label_len,
    float* __restrict__ lse_pred, float* __restrict__ sum_pred,
    int* __restrict__ tg)
{
    __shared__ float ring[3][64 * 64];   // 3 sub-panels x 64 cols x 64 lanes (48 KB)
    __shared__ unsigned chw[16][64];     // choice bits [panel][lane] (4 KB)
    __shared__ int a_s[64];
    __shared__ int rows_s[T_MAX];
    const int w = threadIdx.x >> 6, lane = threadIdx.x & 63;

    if (blockIdx.x < 32) {
        // ---------------- align path: one wave per batch ----------------
        if (threadIdx.x >= 64) return;
        const int b = blockIdx.x;
        const int C = x_len[b], R = label_len[b];
        const int limit = C - R;
        const float* pbb = pb + ((size_t)b << 15);     // b * 512 * 64
        const int P = (C + 31) >> 5;                   // 32-col panels, in [8,16]
        const int SS = (P + 1) >> 1;                   // 64-col sub-panels, in [4,8]
        const float biasR = (lane < R) ? 0.f : NINF;
        const bool isb0 = (lane & 15) == 0;
        const int ninf_i = 0xFF800000;
        float dp = NINF;

#define STAGE(S) { const int s_ = (S); if (s_ < SS) {                          \
        const char* src_ = (const char*)pbb + ((size_t)s_ << 14) + lane * 16;  \
        float* dst_ = ring[s_ % 3];                                            \
        _Pragma("unroll")                                                      \
        for (int k = 0; k < 16; ++k)                                           \
            __builtin_amdgcn_global_load_lds(                                  \
                (const __attribute__((address_space(1))) void*)(src_ + (k << 10)), \
                (__attribute__((address_space(3))) void*)(dst_ + (k << 8)), 16, 0, 0); } }

        STAGE(0) STAGE(1) STAGE(2)
        for (int s = 0; s < SS; ++s) {
            // wait for sub-panel s: allowed outstanding = panels still behind it
            const int rem = SS - 1 - s;
            if (rem >= 2)      asm volatile("s_waitcnt vmcnt(32)" ::: "memory");
            else if (rem == 1) asm volatile("s_waitcnt vmcnt(16)" ::: "memory");
            else               asm volatile("s_waitcnt vmcnt(0)"  ::: "memory");
            const float* sp_ = ring[s % 3];
            #pragma unroll
            for (int half = 0; half < 2; ++half) {
                const int pp = (s << 1) + half;
                if (pp >= P) break;
                unsigned w0 = 0;
                #pragma unroll
                for (int g = 0; g < 2; ++g) {
                    const int g_ = (pp << 1) + g;          // global 16-col group
                    float v[16];
                    #pragma unroll
                    for (int u = 0; u < 16; ++u)
                        v[u] = sp_[(((half << 1) + g) << 4) * 64 + (u << 6) + lane];
                    const bool general = (g_ < 2) || (((g_ << 4) + 15) > limit);
                    #pragma unroll
                    for (int u = 0; u < 16; ++u) {
                        const int kk = (g << 4) + u;       // bit within panel word
                        const int j = (g_ << 4) + u;
                        float val;
                        if (general) {
                            if (g_ == 0 && u == 0) {       // column 0 init
                                dp = (lane == 0) ? v[0] : NINF;
                                continue;
                            }
                            const bool ib = (lane <= j) && (lane >= j - limit) && (lane < R);
                            val = ib ? v[u] : NINF;
                        } else {
                            val = v[u] + biasR;            // off-chain R mask
                        }
                        const int dpb = __float_as_int(dp);
                        const int t1 = __builtin_amdgcn_update_dpp(ninf_i, dpb, 0x111, 0xF, 0xF, false); // row_shr:1
                        const int t2 = __builtin_amdgcn_update_dpp(ninf_i, dpb, 0x142, 0xF, 0xF, false); // row_bcast15
                        const float shifted = __int_as_float(isb0 ? t2 : t1);
                        const bool c = shifted > dp;       // strict, off chain
                        w0 |= (c ? 1u : 0u) << kk;
                        dp = fmaxf(shifted, dp) + val;     // == reference select
                    }
                }
                chw[pp][lane] = w0;
            }
            STAGE(s + 3)
        }
        asm volatile("s_waitcnt vmcnt(0)" ::: "memory");
#undef STAGE

        // backtrack: per-row jumps via highest set bit in cached words
        if (lane == 0) {
            int row = R - 1, j = C - 1;
            while (row > 0 && j >= 0) {
                unsigned word = chw[j >> 5][row];
                unsigned mb = (2u << (j & 31)) - 1;
                unsigned m = word & mb;
                if (m) {
                    int hb = 31 - __clz(m);
                    int aj = (j & ~31) | hb;
                    a_s[row] = aj;
                    row--; j = aj - 1;
                } else {
                    j = (j & ~31) - 1;
                }
            }
            for (int i = row; i >= 0; --i) a_s[i] = 0;
        }
        // parallel interval fill: row i occupies [a_s[i], b_i]
        if (lane < R) {
            int a = a_s[lane];
            int bi = (lane == R - 1) ? (C - 1) : (a_s[lane + 1] - 1);
            for (int j = a; j <= bi; ++j) rows_s[j] = lane;
        }
        for (int j = lane; j < T_MAX; j += 64)
            tg[(b << 9) + j] = (j < C) ? rows_s[j] : -1;
    } else {
        // ---------------- pred rowstats: one wave per row ----------------
        const int r = ((blockIdx.x - 32) << 3) + w;   // [0, NROWS)
        const float* xp = pred + (size_t)r * CLASSES;
        const float4* p4 = (const float4*)xp;

        float4 a0 = p4[lane],       a1 = p4[lane + 64],  a2 = p4[lane + 128];
        float4 a3 = p4[lane + 192], a4 = p4[lane + 256];
        float4 at = make_float4(0.f, 0.f, 0.f, 0.f);
        if (lane < 4) at = p4[320 + lane];

        float sp = __expf(a0.x) + __expf(a0.y) + __expf(a0.z) + __expf(a0.w)
                 + __expf(a1.x) + __expf(a1.y) + __expf(a1.z) + __expf(a1.w)
                 + __expf(a2.x) + __expf(a2.y) + __expf(a2.z) + __expf(a2.w)
                 + __expf(a3.x) + __expf(a3.y) + __expf(a3.z) + __expf(a3.w)
                 + __expf(a4.x) + __expf(a4.y) + __expf(a4.z) + __expf(a4.w);
        float sx = (a0.x + a0.y + a0.z + a0.w) + (a1.x + a1.y + a1.z + a1.w)
                 + (a2.x + a2.y + a2.z + a2.w) + (a3.x + a3.y + a3.z + a3.w)
                 + (a4.x + a4.y + a4.z + a4.w);
        if (lane < 4) {
            sp += __expf(at.x) + __expf(at.y) + __expf(at.z) + __expf(at.w);
            sx += at.x + at.y + at.z + at.w;
        }
        sp = wave_sum64(sp);
        sx = wave_sum64(sx);
        if (lane == 63) {
            lse_pred[r] = __logf(sp);
            sum_pred[r] = sx;
        }
    }
}

// ---------------------------------------------------------------------------
// K3: per-element CE + fused last-block final reduction (agent-scope atomics
// at kernel END only -- this pattern is proven cheap, unlike mid-kernel sync).
// ---------------------------------------------------------------------------
__global__ __launch_bounds__(256) void ce_kernel(
    const float* __restrict__ pred, const int* __restrict__ label,
    const int* __restrict__ x_len,
    const float* __restrict__ lse_pred, const float* __restrict__ sum_pred,
    const float* __restrict__ lse_seq, const float* __restrict__ pb,
    const int* __restrict__ tg, float* __restrict__ partials,
    int* __restrict__ counter, float* __restrict__ out)
{
    int e = blockIdx.x * 256 + threadIdx.x;    // e = t*BATCH + b
    int t = e >> 5, b = e & 31;
    float ce = 0.f;
    if (t < x_len[b]) {
        int row = tg[(b << 9) + t];
        int tgt = label[(b << 6) + row];
        float lp = lse_pred[e];
        float S = sum_pred[e] - (float)CLASSES * lp;        // sum_v log_softmax(pred)
        float lsp_t = pred[(size_t)e * CLASSES + tgt] - lp;
        float conf = __expf(pb[(((size_t)(b << 9) + t) << 6) + row] - lse_seq[e]);
        float smooth = (1.f - conf) * (1.f / (float)(CLASSES - 1));
        ce = -((conf - smooth) * lsp_t + smooth * S);
    }
    ce = wave_sum64(ce);                        // total in lane 63
    __shared__ float sm[4];
    __shared__ int amLast;
    if ((threadIdx.x & 63) == 63) sm[threadIdx.x >> 6] = ce;
    __syncthreads();
    if (threadIdx.x == 0) {
        float p = sm[0] + sm[1] + sm[2] + sm[3];
        __hip_atomic_store(&partials[blockIdx.x], p, __ATOMIC_RELEASE, __HIP_MEMORY_SCOPE_AGENT);
        amLast = (__hip_atomic_fetch_add(counter, 1, __ATOMIC_ACQ_REL, __HIP_MEMORY_SCOPE_AGENT) == 63);
    }
    __syncthreads();
    if (amLast && threadIdx.x < 64) {
        float v = __hip_atomic_load(&partials[threadIdx.x], __ATOMIC_ACQUIRE, __HIP_MEMORY_SCOPE_AGENT);
        for (int o = 32; o; o >>= 1) v += __shfl_down(v, o, 64);
        if (threadIdx.x == 0) out[0] = v * (1.0f / (float)NROWS);
    }
}

extern "C" void kernel_launch(void* const* d_in, const int* in_sizes, int n_in,
                              void* d_out, int out_size, void* d_ws, size_t ws_size,
                              hipStream_t stream) {
    const float* pred      = (const float*)d_in[0];
    const float* seq_pred  = (const float*)d_in[1];
    const int*   label     = (const int*)d_in[2];
    const int*   x_len     = (const int*)d_in[3];
    const int*   label_len = (const int*)d_in[4];
    float* out = (float*)d_out;

    // workspace layout (floats)
    float* ws = (float*)d_ws;
    float* lse_pred = ws;                      // 16384
    float* sum_pred = ws + NROWS;              // 16384
    float* lse_seq  = ws + 2 * NROWS;          // 16384
    float* pb       = ws + 3 * NROWS;          // 32*512*64 = 1048576
    int*   tg       = (int*)(pb + (size_t)BATCH * T_MAX * 64); // 16384 ints
    float* partials = (float*)(tg + NROWS);    // 64
    int*   counter  = (int*)(partials + 64);   // 1

    seq_rowstats_kernel<<<NROWS / 4, 256, 0, stream>>>(seq_pred, label,
                                                       lse_seq, pb, counter);
    fused_align_pred_kernel<<<32 + NROWS / 8, 512, 0, stream>>>(
        pred, pb, x_len, label_len, lse_pred, sum_pred, tg);
    ce_kernel<<<64, 256, 0, stream>>>(pred, label, x_len,
                                      lse_pred, sum_pred, lse_seq, pb, tg,
                                      partials, counter, out);
}